// Round 8
// baseline (218.222 us; speedup 1.0000x reference)
//
#include <hip/hip_runtime.h>

// Collider binary-tree sampling, DEPTH=9, TOTAL_VARS=510, f32 in/out.
// Level d (d=0..7): width 2^(8-d), flat offset 512-(512>>d).
//   d=0: x = eps ; d>0: x[j] = prev[2j] + prev[2j+1] + 0.1*eps[off+j]
//
// Round-8 = round-7 + compiler memory fences. Round-7 failed correctness
// (absmax 9.06): with zero barriers and mixed pointer types (f4 stores vs
// float2/float reads of the same LDS), TBAA let the compiler reorder
// phase-2 reads before phase-1 commits / phase-3 reads before phase-2
// writes. asm volatile("" ::: "memory") at each phase boundary pins the
// order at zero runtime cost (HW DS ops are in-order per wave anyway).
//
// Design: persistent waves (2048 blocks, grid-stride over row-pairs, 16
// iters/wave); register prefetch of NEXT pair issued right after current
// pair's LDS commit (issue-early/write-late); nontemporal load/store.
// Wave-private LDS (4080 B/wave, 16B-aligned row-pairs), zero barriers.
// Pre-committed: if neutral (>=192 us), mixed-stream HBM roofline declared.

#define TOTAL_VARS 510
#define PAIR_FLOATS 1020      // two rows: 4080 B, 16B-aligned
#define SIGMA 0.1f
#define MEMFENCE() asm volatile("" ::: "memory")

typedef float f4 __attribute__((ext_vector_type(4)));

__global__ __launch_bounds__(256) void collider_kernel(
    const float* __restrict__ eps,
    float* __restrict__ out,
    int npairs)
{
    __shared__ __align__(16) float lds[4 * PAIR_FLOATS];   // 16320 B/block

    const int tid  = (int)threadIdx.x;
    const int wave = tid >> 6;
    const int lane = tid & 63;
    float* lw = lds + wave * PAIR_FLOATS;
    f4* l4 = reinterpret_cast<f4*>(lw);

    const int gwave  = (int)blockIdx.x * 4 + wave;
    const int nwaves = (int)gridDim.x * 4;

    // ---- prefetch first pair into registers (255 f4 per wave)
    f4 r0 = (f4)0.f, r1 = (f4)0.f, r2 = (f4)0.f, r3 = (f4)0.f;
    int pair = gwave;
    if (pair < npairs) {
        const f4* g4 = reinterpret_cast<const f4*>(eps + (size_t)pair * PAIR_FLOATS);
        r0 = __builtin_nontemporal_load(&g4[lane]);
        r1 = __builtin_nontemporal_load(&g4[64 + lane]);
        r2 = __builtin_nontemporal_load(&g4[128 + lane]);
        if (lane < 63) r3 = __builtin_nontemporal_load(&g4[192 + lane]);
    }

    for (; pair < npairs; pair += nwaves) {
        // ---- commit prefetched registers to wave-private LDS
        l4[lane]       = r0;
        l4[64 + lane]  = r1;
        l4[128 + lane] = r2;
        if (lane < 63) l4[192 + lane] = r3;

        // ---- issue NEXT pair's loads now; they fly during compute+store
        const int nx = pair + nwaves;
        if (nx < npairs) {
            const f4* g4 = reinterpret_cast<const f4*>(eps + (size_t)nx * PAIR_FLOATS);
            r0 = __builtin_nontemporal_load(&g4[lane]);
            r1 = __builtin_nontemporal_load(&g4[64 + lane]);
            r2 = __builtin_nontemporal_load(&g4[128 + lane]);
            if (lane < 63) r3 = __builtin_nontemporal_load(&g4[192 + lane]);
        }
        MEMFENCE();   // commit (ds_write) ordered before compute (ds_read)

        // ---- tree compute per row, in place in LDS (L0 output == input)
#pragma unroll
        for (int rr = 0; rr < 2; ++rr) {
            float* row = lw + rr * TOTAL_VARS;   // 8B-aligned (2040 B stride)

            const float2 a01 = *reinterpret_cast<const float2*>(row + 4 * lane);
            const float2 a23 = *reinterpret_cast<const float2*>(row + 4 * lane + 2);

            // level 1 (offset 256, width 128)
            const float2 e1 = *reinterpret_cast<const float2*>(row + 256 + 2 * lane);
            const float x1a = a01.x + a01.y + SIGMA * e1.x;
            const float x1b = a23.x + a23.y + SIGMA * e1.y;
            float2 o1; o1.x = x1a; o1.y = x1b;
            *reinterpret_cast<float2*>(row + 256 + 2 * lane) = o1;

            // level 2 (offset 384, width 64)
            const float e2 = row[384 + lane];
            float prev = x1a + x1b + SIGMA * e2;
            row[384 + lane] = prev;

            // levels 3..7: widths 32,16,8,4,2 via shuffle pair-gather
#pragma unroll
            for (int d = 3; d < 8; ++d) {
                const int w   = 256 >> d;
                const int off = 512 - (512 >> d);
                const float a = __shfl(prev, 2 * lane);
                const float b = __shfl(prev, 2 * lane + 1);
                float e = 0.0f;
                if (lane < w) e = row[off + lane];
                const float v = a + b + SIGMA * e;
                if (lane < w) row[off + lane] = v;
                prev = v;
            }
        }
        MEMFENCE();   // compute writes ordered before phase-3 reads

        // ---- LDS -> global, dense f4, nontemporal
        f4* gout4 = reinterpret_cast<f4*>(out + (size_t)pair * PAIR_FLOATS);
#pragma unroll
        for (int c = 0; c < 4; ++c) {
            const int idx = c * 64 + lane;
            if (idx < 255) __builtin_nontemporal_store(l4[idx], &gout4[idx]);
        }
        MEMFENCE();   // phase-3 reads ordered before next iter's commit
    }
}

extern "C" void kernel_launch(void* const* d_in, const int* in_sizes, int n_in,
                              void* d_out, int out_size, void* d_ws, size_t ws_size,
                              hipStream_t stream) {
    const float* eps = (const float*)d_in[0];
    float* out = (float*)d_out;
    const int N = in_sizes[0] / TOTAL_VARS;  // 262144
    const int npairs = N / 2;                // 131072

    const int blocks = 2048;                 // 8 blocks/CU co-resident; 16 iters/wave
    collider_kernel<<<blocks, 256, 0, stream>>>(eps, out, npairs);
}

// Round 9
// 206.092 us; speedup vs baseline: 1.0589x; 1.0589x over previous
//
#include <hip/hip_runtime.h>

// Collider binary-tree sampling, DEPTH=9, TOTAL_VARS=510, f32 in/out.
// Level d (d=0..7): width 2^(8-d), flat offset 512-(512>>d).
//   d=0: x = eps ; d>0: x[j] = prev[2j] + prev[2j+1] + 0.1*eps[off+j]
//
// FINAL (revert to round-5 best: 196.4 us = 5.45 TB/s, 87% of the 6.29 TB/s
// mixed-stream copy ceiling). Hypothesis ledger:
//   R2 direct float2            197.9 us
//   R3 block-barrier LDS stage  216.2 us  (barriers hurt)
//   R4 dense float2+packed tail 204.7 us
//   R5 wave-private LDS stage   196.4 us  <- best
//   R8 persistent+prefetch+NT   218.2 us  (NT bypasses L2; T14 null confirmed)
// Bytes are ideal (535+535 MB). All access-pattern variants converge at
// ~5.4 TB/s -> practical HBM roofline for this mixed read+write stream.
//
// Design: one wave owns TWO consecutive rows (1020 floats = 4080 B = 255 x
// 16 B, so every row-pair base is 16B-aligned -> all global I/O is dense
// float4). Phase 1: global -> own LDS region. Phase 2: tree compute in
// place in LDS (L0 output == input; deeper levels overwrite their eps
// slots). Phase 3: own LDS region -> global. No __syncthreads: each wave
// touches only its own LDS; same-wave ds ordering comes from lgkmcnt.

#define TOTAL_VARS 510
#define SIGMA 0.1f

__global__ __launch_bounds__(256) void collider_kernel(
    const float* __restrict__ eps,
    float* __restrict__ out,
    int N)
{
    __shared__ __align__(16) float lds[4 * 1020];   // 16320 B, per-wave 4080 B (16B-aligned)

    const int tid  = (int)threadIdx.x;
    const int wave = tid >> 6;
    const int lane = tid & 63;

    const size_t pair = (size_t)blockIdx.x * 4 + wave;      // row-pair index (N/2 total)
    const float* __restrict__ gin = eps + pair * 1020;
    float* __restrict__ gout      = out + pair * 1020;
    float* lw = lds + wave * 1020;

    // ---- phase 1: global -> LDS, dense float4 (255 per wave)
    const float4* __restrict__ g4 = reinterpret_cast<const float4*>(gin);
    float4* l4 = reinterpret_cast<float4*>(lw);
#pragma unroll
    for (int c = 0; c < 4; ++c) {
        const int idx = c * 64 + lane;
        if (idx < 255) l4[idx] = g4[idx];
    }

    // ---- phase 2: tree compute per row, in place in LDS
#pragma unroll
    for (int rr = 0; rr < 2; ++rr) {
        float* row = lw + rr * TOTAL_VARS;   // 2040 B stride: 8B-aligned, float2 ok

        // level 0: x = eps, already in place; read leaves 4l..4l+3
        const float2 a01 = *reinterpret_cast<const float2*>(row + 4 * lane);
        const float2 a23 = *reinterpret_cast<const float2*>(row + 4 * lane + 2);

        // level 1 (offset 256, width 128)
        const float2 e1 = *reinterpret_cast<const float2*>(row + 256 + 2 * lane);
        const float x1a = a01.x + a01.y + SIGMA * e1.x;
        const float x1b = a23.x + a23.y + SIGMA * e1.y;
        float2 o1; o1.x = x1a; o1.y = x1b;
        *reinterpret_cast<float2*>(row + 256 + 2 * lane) = o1;

        // level 2 (offset 384, width 64)
        const float e2 = row[384 + lane];
        float prev = x1a + x1b + SIGMA * e2;
        row[384 + lane] = prev;

        // levels 3..7: widths 32,16,8,4,2 via shuffle pair-gather
#pragma unroll
        for (int d = 3; d < 8; ++d) {
            const int w   = 256 >> d;
            const int off = 512 - (512 >> d);
            const float a = __shfl(prev, 2 * lane);
            const float b = __shfl(prev, 2 * lane + 1);
            float e = 0.0f;
            if (lane < w) e = row[off + lane];
            const float v = a + b + SIGMA * e;
            if (lane < w) row[off + lane] = v;
            prev = v;
        }
    }

    // ---- phase 3: LDS -> global, dense float4 (255 per wave)
#pragma unroll
    for (int c = 0; c < 4; ++c) {
        const int idx = c * 64 + lane;
        if (idx < 255) *reinterpret_cast<float4*>(gout + 4 * idx) = l4[idx];
    }
}

extern "C" void kernel_launch(void* const* d_in, const int* in_sizes, int n_in,
                              void* d_out, int out_size, void* d_ws, size_t ws_size,
                              hipStream_t stream) {
    const float* eps = (const float*)d_in[0];
    float* out = (float*)d_out;
    const int N = in_sizes[0] / TOTAL_VARS;  // 262144 (even)

    const int pairs = N / 2;                 // 131072 row-pairs
    const int blocks = pairs / 4;            // 4 waves per block -> 32768 blocks
    collider_kernel<<<blocks, 256, 0, stream>>>(eps, out, N);
}